// Round 9
// baseline (1225.122 us; speedup 1.0000x reference)
//
#include <hip/hip_runtime.h>
#include <stdint.h>
#include <stddef.h>
#include <vector>
#include <algorithm>
#include <utility>

// Problem constants (B=2, L=4096, D=256, H=8, K=sqrt(L)=64, 10 Lloyd iters)
#define NPTS 8192
#define DIM  256
#define KC   64
#define LSEQ 4096
#define NB   2
#define KM_ITERS 10
#define NCHUNK 64     // 8192/128 points per summation chunk (bit-exact structure)
#define NBLK 64       // persistent kmeans blocks (block = chunk = cluster)
#define XPITCH 260    // padded LDS row for X tile
#define CSP 257       // padded LDS row for centroid tile (row-major)

// JAX threefry mode: 1 = partitionable (default since jax 0.4.36), 0 = original
#define JAX_THREEFRY_PARTITIONABLE 1

// ---------------- static device scratch (fully rewritten every call) --------
__device__ float g_R[NPTS * DIM];          // 8 MB   rotated points (read-only in kmeans)
__device__ float g_xsq[NPTS];              // 32 KB  per-point squared norm
__device__ float g_centC[KC * DIM];        // 64 KB  centroids row-major [k][d] (SC1)
__device__ float g_csq[KC];                // per-centroid squared norm (SC1)
__device__ int   g_idx[NPTS];              // final assignments (= cid)
__device__ float g_part[NCHUNK][KC][DIM];  // 4 MB   chunked segment sums (SC1)
__device__ int   g_pcnt[NCHUNK][KC];       // chunked counts (SC1)

// Flag-tree barrier state; monotone across graph replays (each launch executes
// the same number of barriers; each block reads its own flag at entry as base).
__device__ unsigned g_arrive[NBLK * 16];   // block c uses g_arrive[c*16]
__device__ unsigned g_release2;            // release word (monotone)

// ---- relaxed agent-scope (SC1, L3-coherent) scalar access -------------------
// Validated correct in round 6 (cross-XCD visible with only vmcnt-drain +
// relaxed flags; no fences). All uses below are wave-coalesced.
__device__ __forceinline__ float coh_ld(const float* p) {
  return __hip_atomic_load(p, __ATOMIC_RELAXED, __HIP_MEMORY_SCOPE_AGENT);
}
__device__ __forceinline__ int coh_ldi(const int* p) {
  return __hip_atomic_load(p, __ATOMIC_RELAXED, __HIP_MEMORY_SCOPE_AGENT);
}
__device__ __forceinline__ void coh_st(float* p, float v) {
  __hip_atomic_store(p, v, __ATOMIC_RELAXED, __HIP_MEMORY_SCOPE_AGENT);
}
__device__ __forceinline__ void coh_sti(int* p, int v) {
  __hip_atomic_store(p, v, __ATOMIC_RELAXED, __HIP_MEMORY_SCOPE_AGENT);
}

// Fence-free flag-tree barrier: __syncthreads drains vmcnt (SC1 stores are at
// the coherence point when acked), then relaxed flag stores/polls. No
// wbl2/inv is ever emitted (no acquire/release anywhere).
__device__ __forceinline__ void grid_barrier(int c, unsigned target) {
  __syncthreads();  // drains vmcnt: this block's SC1 stores are globally visible
  const int t = threadIdx.x;
  if (t == 0) {
    __hip_atomic_store(&g_arrive[c * 16], target, __ATOMIC_RELAXED,
                       __HIP_MEMORY_SCOPE_AGENT);
  }
  if (c == 0) {
    if (t < NBLK) {
      while (__hip_atomic_load(&g_arrive[t * 16], __ATOMIC_RELAXED,
                               __HIP_MEMORY_SCOPE_AGENT) < target) {
        __builtin_amdgcn_s_sleep(1);
      }
    }
    __syncthreads();
    if (t == 0) {
      __hip_atomic_store(&g_release2, target, __ATOMIC_RELAXED,
                         __HIP_MEMORY_SCOPE_AGENT);
    }
  } else {
    if (t == 0) {
      while (__hip_atomic_load(&g_release2, __ATOMIC_RELAXED,
                               __HIP_MEMORY_SCOPE_AGENT) < target) {
        __builtin_amdgcn_s_sleep(1);
      }
    }
  }
  __syncthreads();
}

// ---------------- host threefry2x32 (exact JAX semantics) -------------------
static inline uint32_t rotl32(uint32_t x, int r) { return (x << r) | (x >> (32 - r)); }

static void threefry2x32(uint32_t k0, uint32_t k1, uint32_t x0, uint32_t x1,
                         uint32_t& o0, uint32_t& o1) {
  const uint32_t ks0 = k0, ks1 = k1, ks2 = k0 ^ k1 ^ 0x1BD11BDAu;
  const int r1[4] = {13, 15, 26, 6}, r2[4] = {17, 29, 16, 24};
  x0 += ks0; x1 += ks1;
  for (int i = 0; i < 4; ++i) { x0 += x1; x1 = rotl32(x1, r1[i]); x1 ^= x0; }
  x0 += ks1; x1 += ks2 + 1u;
  for (int i = 0; i < 4; ++i) { x0 += x1; x1 = rotl32(x1, r2[i]); x1 ^= x0; }
  x0 += ks2; x1 += ks0 + 2u;
  for (int i = 0; i < 4; ++i) { x0 += x1; x1 = rotl32(x1, r1[i]); x1 ^= x0; }
  x0 += ks0; x1 += ks1 + 3u;
  for (int i = 0; i < 4; ++i) { x0 += x1; x1 = rotl32(x1, r2[i]); x1 ^= x0; }
  x0 += ks1; x1 += ks2 + 4u;
  for (int i = 0; i < 4; ++i) { x0 += x1; x1 = rotl32(x1, r1[i]); x1 ^= x0; }
  x0 += ks2; x1 += ks0 + 5u;
  o0 = x0; o1 = x1;
}

struct InitIdx { int v[KC]; };

// jax.random.choice(key(42), 8192, (64,), replace=False)
//  = permutation(key, arange(8192))[:64]  (2-round threefry shuffle)
static InitIdx compute_init_indices() {
  uint32_t k0 = 0u, k1 = 42u;  // jax.random.key(42) -> [0, 42]
  std::vector<int> val(NPTS);
  for (int i = 0; i < NPTS; ++i) val[i] = i;
  std::vector<std::pair<uint32_t, int>> kv(NPTS);
  for (int round = 0; round < 2; ++round) {
    uint32_t nk0, nk1, sk0, sk1;
#if JAX_THREEFRY_PARTITIONABLE
    threefry2x32(k0, k1, 0u, 0u, nk0, nk1);
    threefry2x32(k0, k1, 0u, 1u, sk0, sk1);
    k0 = nk0; k1 = nk1;
    for (int i = 0; i < NPTS; ++i) {
      uint32_t o0, o1;
      threefry2x32(sk0, sk1, 0u, (uint32_t)i, o0, o1);
      kv[i] = std::make_pair(o0 ^ o1, val[i]);
    }
#else
    uint32_t a0, a1, b0, b1;
    threefry2x32(k0, k1, 0u, 2u, a0, a1);
    threefry2x32(k0, k1, 1u, 3u, b0, b1);
    nk0 = a0; nk1 = b0; sk0 = a1; sk1 = b1;
    k0 = nk0; k1 = nk1;
    for (int i = 0; i < NPTS / 2; ++i) {
      uint32_t o0, o1;
      threefry2x32(sk0, sk1, (uint32_t)i, (uint32_t)(i + NPTS / 2), o0, o1);
      kv[i] = std::make_pair(o0, 0);
      kv[i + NPTS / 2] = std::make_pair(o1, 0);
    }
    for (int i = 0; i < NPTS; ++i) kv[i].second = val[i];
#endif
    std::stable_sort(kv.begin(), kv.end(),
                     [](const std::pair<uint32_t, int>& a,
                        const std::pair<uint32_t, int>& b) { return a.first < b.first; });
    for (int i = 0; i < NPTS; ++i) val[i] = kv[i].second;
  }
  InitIdx ii;
  for (int k = 0; k < KC; ++k) ii.v[k] = val[k];
  return ii;
}

// ---------------- kernels ---------------------------------------------------

// Fused R-GEMM + xsq (unchanged).
__global__ void __launch_bounds__(256) k_R_xsq(const float* __restrict__ qk,
                                               const float* __restrict__ W) {
  __shared__ float q[8][DIM];
  const int blk = blockIdx.x;               // 0..1023
  const int b = blk / (LSEQ / 8);
  const int r0 = (blk % (LSEQ / 8)) * 8;
  const int t = threadIdx.x;
  for (int r = 0; r < 8; ++r)
    q[r][t] = qk[((size_t)b * LSEQ + r0 + r) * DIM + t];
  __syncthreads();
  float acc[8] = {0.f, 0.f, 0.f, 0.f, 0.f, 0.f, 0.f, 0.f};
  const float* Wb = W + (size_t)b * DIM * DIM;
  for (int d = 0; d < DIM; ++d) {
    const float w = Wb[d * DIM + t];
#pragma unroll
    for (int r = 0; r < 8; ++r) acc[r] = fmaf(q[r][d], w, acc[r]);
  }
  for (int r = 0; r < 8; ++r)
    g_R[((size_t)b * LSEQ + r0 + r) * DIM + t] = acc[r];
  __syncthreads();
  for (int r = 0; r < 8; ++r) q[r][t] = acc[r];
  __syncthreads();
  const int w = t >> 6, lane = t & 63;
#pragma unroll
  for (int rr = 0; rr < 2; ++rr) {
    const int r = w * 2 + rr;
    const float4 x = *(const float4*)&q[r][lane * 4];
    float s = x.x * x.x + x.y * x.y + x.z * x.z + x.w * x.w;
    for (int o = 32; o > 0; o >>= 1) s += __shfl_xor(s, o);
    if (lane == 0) g_xsq[(size_t)b * LSEQ + r0 + r] = s;
  }
}

// Persistent k-means. All fp chains verbatim round-4 (Cs now read row-major:
// cr_j = C[ct+j][d..d+3] feeds the identical fmaf nesting -> same bits).
__global__ void __launch_bounds__(256) k_kmeans(InitIdx ii) {
  __shared__ float Cs[KC * CSP];      // 65.8 KB row-major centroid tile (pitch 257)
  __shared__ float Xs[64 * XPITCH];   // 66.56 KB X tile / upA staging (pitch 260)
  __shared__ int idx_s[128];
  __shared__ float red[256];
  __shared__ int cnt_s[KC];
  __shared__ unsigned base_s;
  const int t = threadIdx.x;
  const int c = blockIdx.x;           // chunk 0..63 (also cluster id for upB)
  const int p0 = c * 128;
  const int ptg = t >> 4;             // 0..15 -> 4-point group
  const int ctg = t & 15;             // 0..15 -> 4-cluster group
  const int ct = ctg * 4;

  if (t == 0)
    base_s = __hip_atomic_load(&g_arrive[c * 16], __ATOMIC_RELAXED,
                               __HIP_MEMORY_SCOPE_AGENT);
  __syncthreads();
  const unsigned base = base_s;
  unsigned bar = 0;

  // ---- init centroid k=c (exact chain); write coalesced (lane = dim) ----
  float myc;
  {
    const float cv = g_R[(size_t)ii.v[c] * DIM + t];
    myc = cv;
    coh_st(&g_centC[c * DIM + t], cv);
    red[t] = cv * cv;
    __syncthreads();
    for (int o = 128; o > 0; o >>= 1) {
      if (t < o) red[t] += red[t + o];
      __syncthreads();
    }
    if (t == 0) coh_st(&g_csq[c], red[0]);
  }
  grid_barrier(c, base + (++bar));

  for (int it = 0; it <= KM_ITERS; ++it) {
    const bool final_pass = (it == KM_ITERS);

    // ---- load Cs row-major (coalesced SC1 loads; linear i = k*256+d) ----
    for (int i = t; i < KC * DIM; i += 256) {
      const int k2 = i >> 8, d2 = i & 255;
      Cs[k2 * CSP + d2] = coh_ld(&g_centC[i]);
    }
    const float cs0 = coh_ld(&g_csq[ct + 0]);
    const float cs1 = coh_ld(&g_csq[ct + 1]);
    const float cs2 = coh_ld(&g_csq[ct + 2]);
    const float cs3 = coh_ld(&g_csq[ct + 3]);

    // ---- assign two 64-point halves (exact round-4 fmaf/argmin chains) ----
    for (int h = 0; h < 2; ++h) {
      __syncthreads();  // protect Xs reuse (and cover Cs load on h==0)
      for (int idx = t; idx < 64 * (DIM / 4); idx += 256) {
        const int r = idx >> 6;
        const int dq = idx & 63;
        *(float4*)&Xs[r * XPITCH + dq * 4] =
            *(const float4*)(g_R + (size_t)(p0 + h * 64 + r) * DIM + dq * 4);
      }
      __syncthreads();

      float acc[4][4];
#pragma unroll
      for (int r = 0; r < 4; ++r)
#pragma unroll
        for (int j = 0; j < 4; ++j) acc[r][j] = 0.f;

#pragma unroll 4
      for (int d = 0; d < DIM; d += 4) {
        const float4 cr0 = *(const float4*)&Cs[(ct + 0) * CSP + d];
        const float4 cr1 = *(const float4*)&Cs[(ct + 1) * CSP + d];
        const float4 cr2 = *(const float4*)&Cs[(ct + 2) * CSP + d];
        const float4 cr3 = *(const float4*)&Cs[(ct + 3) * CSP + d];
#pragma unroll
        for (int r = 0; r < 4; ++r) {
          const float4 x = *(const float4*)&Xs[(ptg * 4 + r) * XPITCH + d];
          // identical chains: innermost fmaf is x.w*C[k][d+3] + acc
          acc[r][0] = fmaf(x.x, cr0.x, fmaf(x.y, cr0.y, fmaf(x.z, cr0.z, fmaf(x.w, cr0.w, acc[r][0]))));
          acc[r][1] = fmaf(x.x, cr1.x, fmaf(x.y, cr1.y, fmaf(x.z, cr1.z, fmaf(x.w, cr1.w, acc[r][1]))));
          acc[r][2] = fmaf(x.x, cr2.x, fmaf(x.y, cr2.y, fmaf(x.z, cr2.z, fmaf(x.w, cr2.w, acc[r][2]))));
          acc[r][3] = fmaf(x.x, cr3.x, fmaf(x.y, cr3.y, fmaf(x.z, cr3.z, fmaf(x.w, cr3.w, acc[r][3]))));
        }
      }

#pragma unroll
      for (int r = 0; r < 4; ++r) {
        const int pl = h * 64 + ptg * 4 + r;
        const float xs = g_xsq[p0 + pl];
        float best = 3.4e38f;
        int bk = 0;
        {
          float v;
          v = (xs - 2.0f * acc[r][0]) + cs0; if (v < best) { best = v; bk = ct + 0; }
          v = (xs - 2.0f * acc[r][1]) + cs1; if (v < best) { best = v; bk = ct + 1; }
          v = (xs - 2.0f * acc[r][2]) + cs2; if (v < best) { best = v; bk = ct + 2; }
          v = (xs - 2.0f * acc[r][3]) + cs3; if (v < best) { best = v; bk = ct + 3; }
        }
#pragma unroll
        for (int o = 1; o < 16; o <<= 1) {
          const float ov = __shfl_xor(best, o);
          const int obk = __shfl_xor(bk, o);
          if (ov < best || (ov == best && obk < bk)) { best = ov; bk = obk; }
        }
        if (ctg == 0) {
          idx_s[pl] = bk;
          if (final_pass) g_idx[p0 + pl] = bk;
        }
      }
    }
    if (final_pass) break;

    // ---- upA (exact round-4 accumulation chains, in registers) ----
    {
      __syncthreads();
      const int k = t >> 2;   // cluster 0..63
      const int dg = t & 3;   // dims dg*64 .. dg*64+63
      float4 s[16];
#pragma unroll
      for (int q = 0; q < 16; ++q) s[q] = make_float4(0.f, 0.f, 0.f, 0.f);
      int cnt = 0;
      for (int pl = 0; pl < 64; ++pl) {
        if (idx_s[pl] == k) {
          const float4* row = (const float4*)(g_R + (size_t)(p0 + pl) * DIM + dg * 64);
#pragma unroll
          for (int q = 0; q < 16; ++q) {
            const float4 x = row[q];
            s[q].x += x.x; s[q].y += x.y; s[q].z += x.z; s[q].w += x.w;
          }
          cnt++;
        }
      }
      for (int pl = 64; pl < 128; ++pl) {
        if (idx_s[pl] == k) {
          const float4* row = (const float4*)(&Xs[(pl - 64) * XPITCH + dg * 64]);
#pragma unroll
          for (int q = 0; q < 16; ++q) {
            const float4 x = row[q];
            s[q].x += x.x; s[q].y += x.y; s[q].z += x.z; s[q].w += x.w;
          }
          cnt++;
        }
      }
      // stage through LDS (Xs no longer needed this iter), then coalesced SC1
      __syncthreads();  // all Xs reads done
      // stage float-index: dg*4160 + q*260 + k*4 + j  (2-way banks both sides)
#pragma unroll
      for (int q = 0; q < 16; ++q)
        *(float4*)&Xs[dg * 4160 + q * 260 + (k << 2)] = s[q];
      if (dg == 0) cnt_s[k] = cnt;
      __syncthreads();
      for (int L = t; L < KC * DIM; L += 256) {   // L = k2*256 + d2 (coalesced)
        const int k2 = L >> 8, d2 = L & 255;
        const int dg2 = d2 >> 6, q2 = (d2 >> 2) & 15, j2 = d2 & 3;
        coh_st(&g_part[c][k2][d2], Xs[dg2 * 4160 + q2 * 260 + (k2 << 2) + j2]);
      }
      if (t < KC) coh_sti(&g_pcnt[c][t], cnt_s[t]);
    }
    grid_barrier(c, base + (++bar));  // A: partials at coherence point

    // ---- upB for cluster c (exact ascending chunk-order chain) ----
    {
      float v[NCHUNK];
#pragma unroll
      for (int ch = 0; ch < NCHUNK; ++ch) v[ch] = coh_ld(&g_part[ch][c][t]);
      float s = 0.f;
#pragma unroll
      for (int ch = 0; ch < NCHUNK; ++ch) s += v[ch];
      int cnt = 0;
#pragma unroll 4
      for (int ch = 0; ch < NCHUNK; ++ch) cnt += coh_ldi(&g_pcnt[ch][c]);
      const float nc = (cnt > 0) ? (s / (float)cnt) : myc;
      myc = nc;
      coh_st(&g_centC[c * DIM + t], nc);   // coalesced (lane = dim)
      red[t] = nc * nc;
      __syncthreads();
      for (int o = 128; o > 0; o >>= 1) {
        if (t < o) red[t] += red[t + o];
        __syncthreads();
      }
      if (t == 0) coh_st(&g_csq[c], red[0]);
    }
    grid_barrier(c, base + (++bar));  // B: new centroids visible
  }
}

// mask write: out[b,h,i,j] = (cid[b,i]==cid[b,j]) ? 0 : -10000. 16 rows/block.
__global__ void __launch_bounds__(256) k_mask(float* __restrict__ out, int H) {
  const int blk = blockIdx.x;
  const int tiles = LSEQ / 16;  // 256
  const int b = blk / (H * tiles);
  const int h = (blk / tiles) % H;
  const int tile = blk % tiles;
  const int t = threadIdx.x;
  __shared__ int cid[LSEQ];  // 16 KB
  for (int j = t; j < LSEQ; j += 256) cid[j] = g_idx[b * LSEQ + j];
  __syncthreads();
  const size_t base = ((size_t)(b * H + h) * LSEQ + (size_t)tile * 16) * LSEQ;
  for (int r = 0; r < 16; ++r) {
    const int my = cid[tile * 16 + r];
    float4* orow = (float4*)(out + base + (size_t)r * LSEQ);
#pragma unroll
    for (int s = 0; s < 4; ++s) {
      const int c4 = s * 256 + t;
      const int j = c4 * 4;
      float4 v;
      v.x = (cid[j + 0] == my) ? 0.f : -10000.f;
      v.y = (cid[j + 1] == my) ? 0.f : -10000.f;
      v.z = (cid[j + 2] == my) ? 0.f : -10000.f;
      v.w = (cid[j + 3] == my) ? 0.f : -10000.f;
      orow[c4] = v;
    }
  }
}

// ---------------- launch -----------------------------------------------------
extern "C" void kernel_launch(void* const* d_in, const int* in_sizes, int n_in,
                              void* d_out, int out_size, void* d_ws, size_t ws_size,
                              hipStream_t stream) {
  const float* qk = (const float*)d_in[0];
  const float* W = (const float*)d_in[1];
  const int H = out_size / (NB * LSEQ * LSEQ);  // 8

  const InitIdx ii = compute_init_indices();  // pure host integer math

  k_R_xsq<<<NB * (LSEQ / 8), 256, 0, stream>>>(qk, W);
  k_kmeans<<<NBLK, 256, 0, stream>>>(ii);
  k_mask<<<NB * H * (LSEQ / 16), 256, 0, stream>>>((float*)d_out, H);
}

// Round 10
// 755.303 us; speedup vs baseline: 1.6220x; 1.6220x over previous
//
#include <hip/hip_runtime.h>
#include <stdint.h>
#include <stddef.h>
#include <vector>
#include <algorithm>
#include <utility>

// Problem constants (B=2, L=4096, D=256, H=8, K=sqrt(L)=64, 10 Lloyd iters)
#define NPTS 8192
#define DIM  256
#define KC   64
#define LSEQ 4096
#define NB   2
#define KM_ITERS 10
#define NCHUNK 64     // 8192/128 points per summation chunk (bit-exact structure)
#define NBLK 64       // persistent kmeans blocks (block = chunk = cluster)
#define XPITCH 260    // padded LDS row for X tile (float4-aligned: 1040 B)

// JAX threefry mode: 1 = partitionable (default since jax 0.4.36), 0 = original
#define JAX_THREEFRY_PARTITIONABLE 1

// ---------------- static device scratch (fully rewritten every call) --------
__device__ float g_R[NPTS * DIM];          // 8 MB   rotated points (read-only in kmeans)
__device__ float g_xsq[NPTS];              // 32 KB  per-point squared norm
__device__ float g_centT[DIM * KC];        // 64 KB  centroids transposed [d][k]
__device__ float g_csq[KC];                // per-centroid squared norm
__device__ int   g_idx[NPTS];              // final assignments (= cid)
__device__ float g_part[NCHUNK][KC][DIM];  // 4 MB   chunked segment sums
__device__ int   g_pcnt[NCHUNK][KC];       // chunked counts

// Flag-tree grid barrier state (monotone across graph replays; each block
// reads its own flag at entry as base — deterministic per replay).
__device__ unsigned g_arrive[NBLK * 16];   // block c uses g_arrive[c*16]
__device__ unsigned g_release2;            // release word (monotone)

// Round-7 barrier (best measured): arrival release-store (one L2 wb), block-0
// parallel relaxed polls, single release store + acquire-inv per block.
__device__ __forceinline__ void grid_barrier(int c, unsigned target) {
  __syncthreads();
  const int t = threadIdx.x;
  if (t == 0) {
    __hip_atomic_store(&g_arrive[c * 16], target, __ATOMIC_RELEASE,
                       __HIP_MEMORY_SCOPE_AGENT);
  }
  if (c == 0) {
    if (t < NBLK) {
      while (__hip_atomic_load(&g_arrive[t * 16], __ATOMIC_RELAXED,
                               __HIP_MEMORY_SCOPE_AGENT) < target) {
        __builtin_amdgcn_s_sleep(1);
      }
    }
    __syncthreads();
    if (t == 0) {
      __hip_atomic_store(&g_release2, target, __ATOMIC_RELEASE,
                         __HIP_MEMORY_SCOPE_AGENT);
      (void)__hip_atomic_load(&g_release2, __ATOMIC_ACQUIRE,
                              __HIP_MEMORY_SCOPE_AGENT);  // single inv
    }
  } else {
    if (t == 0) {
      while (__hip_atomic_load(&g_release2, __ATOMIC_RELAXED,
                               __HIP_MEMORY_SCOPE_AGENT) < target) {
        __builtin_amdgcn_s_sleep(2);
      }
      (void)__hip_atomic_load(&g_release2, __ATOMIC_ACQUIRE,
                              __HIP_MEMORY_SCOPE_AGENT);  // single inv
    }
  }
  __syncthreads();
}

// ---------------- host threefry2x32 (exact JAX semantics) -------------------
static inline uint32_t rotl32(uint32_t x, int r) { return (x << r) | (x >> (32 - r)); }

static void threefry2x32(uint32_t k0, uint32_t k1, uint32_t x0, uint32_t x1,
                         uint32_t& o0, uint32_t& o1) {
  const uint32_t ks0 = k0, ks1 = k1, ks2 = k0 ^ k1 ^ 0x1BD11BDAu;
  const int r1[4] = {13, 15, 26, 6}, r2[4] = {17, 29, 16, 24};
  x0 += ks0; x1 += ks1;
  for (int i = 0; i < 4; ++i) { x0 += x1; x1 = rotl32(x1, r1[i]); x1 ^= x0; }
  x0 += ks1; x1 += ks2 + 1u;
  for (int i = 0; i < 4; ++i) { x0 += x1; x1 = rotl32(x1, r2[i]); x1 ^= x0; }
  x0 += ks2; x1 += ks0 + 2u;
  for (int i = 0; i < 4; ++i) { x0 += x1; x1 = rotl32(x1, r1[i]); x1 ^= x0; }
  x0 += ks0; x1 += ks1 + 3u;
  for (int i = 0; i < 4; ++i) { x0 += x1; x1 = rotl32(x1, r2[i]); x1 ^= x0; }
  x0 += ks1; x1 += ks2 + 4u;
  for (int i = 0; i < 4; ++i) { x0 += x1; x1 = rotl32(x1, r1[i]); x1 ^= x0; }
  x0 += ks2; x1 += ks0 + 5u;
  o0 = x0; o1 = x1;
}

struct InitIdx { int v[KC]; };

// jax.random.choice(key(42), 8192, (64,), replace=False)
//  = permutation(key, arange(8192))[:64]  (2-round threefry shuffle)
static InitIdx compute_init_indices() {
  uint32_t k0 = 0u, k1 = 42u;  // jax.random.key(42) -> [0, 42]
  std::vector<int> val(NPTS);
  for (int i = 0; i < NPTS; ++i) val[i] = i;
  std::vector<std::pair<uint32_t, int>> kv(NPTS);
  for (int round = 0; round < 2; ++round) {
    uint32_t nk0, nk1, sk0, sk1;
#if JAX_THREEFRY_PARTITIONABLE
    threefry2x32(k0, k1, 0u, 0u, nk0, nk1);
    threefry2x32(k0, k1, 0u, 1u, sk0, sk1);
    k0 = nk0; k1 = nk1;
    for (int i = 0; i < NPTS; ++i) {
      uint32_t o0, o1;
      threefry2x32(sk0, sk1, 0u, (uint32_t)i, o0, o1);
      kv[i] = std::make_pair(o0 ^ o1, val[i]);
    }
#else
    uint32_t a0, a1, b0, b1;
    threefry2x32(k0, k1, 0u, 2u, a0, a1);
    threefry2x32(k0, k1, 1u, 3u, b0, b1);
    nk0 = a0; nk1 = b0; sk0 = a1; sk1 = b1;
    k0 = nk0; k1 = nk1;
    for (int i = 0; i < NPTS / 2; ++i) {
      uint32_t o0, o1;
      threefry2x32(sk0, sk1, (uint32_t)i, (uint32_t)(i + NPTS / 2), o0, o1);
      kv[i] = std::make_pair(o0, 0);
      kv[i + NPTS / 2] = std::make_pair(o1, 0);
    }
    for (int i = 0; i < NPTS; ++i) kv[i].second = val[i];
#endif
    std::stable_sort(kv.begin(), kv.end(),
                     [](const std::pair<uint32_t, int>& a,
                        const std::pair<uint32_t, int>& b) { return a.first < b.first; });
    for (int i = 0; i < NPTS; ++i) val[i] = kv[i].second;
  }
  InitIdx ii;
  for (int k = 0; k < KC; ++k) ii.v[k] = val[k];
  return ii;
}

// ---------------- kernels ---------------------------------------------------

// Fused R-GEMM + xsq (unchanged).
__global__ void __launch_bounds__(256) k_R_xsq(const float* __restrict__ qk,
                                               const float* __restrict__ W) {
  __shared__ float q[8][DIM];
  const int blk = blockIdx.x;               // 0..1023
  const int b = blk / (LSEQ / 8);
  const int r0 = (blk % (LSEQ / 8)) * 8;
  const int t = threadIdx.x;
  for (int r = 0; r < 8; ++r)
    q[r][t] = qk[((size_t)b * LSEQ + r0 + r) * DIM + t];
  __syncthreads();
  float acc[8] = {0.f, 0.f, 0.f, 0.f, 0.f, 0.f, 0.f, 0.f};
  const float* Wb = W + (size_t)b * DIM * DIM;
  for (int d = 0; d < DIM; ++d) {
    const float w = Wb[d * DIM + t];
#pragma unroll
    for (int r = 0; r < 8; ++r) acc[r] = fmaf(q[r][d], w, acc[r]);
  }
  for (int r = 0; r < 8; ++r)
    g_R[((size_t)b * LSEQ + r0 + r) * DIM + t] = acc[r];
  __syncthreads();
  for (int r = 0; r < 8; ++r) q[r][t] = acc[r];
  __syncthreads();
  const int w = t >> 6, lane = t & 63;
#pragma unroll
  for (int rr = 0; rr < 2; ++rr) {
    const int r = w * 2 + rr;
    const float4 x = *(const float4*)&q[r][lane * 4];
    float s = x.x * x.x + x.y * x.y + x.z * x.z + x.w * x.w;
    for (int o = 32; o > 0; o >>= 1) s += __shfl_xor(s, o);
    if (lane == 0) g_xsq[(size_t)b * LSEQ + r0 + r] = s;
  }
}

// Persistent k-means, 64 blocks x 1024 threads (4 waves/SIMD for latency
// hiding). Every fp chain is the same per-(point,cluster) / per-(cluster,dim)
// sequence as rounds 4-8 -> bit-identical trajectory; only the thread->work
// mapping changed (finer partition of independent chains).
__global__ void __launch_bounds__(1024) k_kmeans(InitIdx ii) {
  __shared__ float Cs[DIM * KC];      // 64 KB transposed Cs[d][k]
  __shared__ float Xs[64 * XPITCH];   // 66.56 KB (padded rows)
  __shared__ int idx_s[128];
  __shared__ float red[256];
  __shared__ unsigned base_s;
  const int t = threadIdx.x;          // 0..1023
  const int c = blockIdx.x;           // chunk 0..63 (also cluster id for upB)
  const int p0 = c * 128;
  const int plg = t >> 4;             // point 0..63 within current half
  const int cg = t & 15;              // 4-cluster group 0..15
  const int ct = cg * 4;

  if (t == 0)
    base_s = __hip_atomic_load(&g_arrive[c * 16], __ATOMIC_RELAXED,
                               __HIP_MEMORY_SCOPE_AGENT);
  __syncthreads();
  const unsigned base = base_s;
  unsigned bar = 0;

  // ---- init centroid k=c (exact chain, threads 0..255) ----
  float myc = 0.f;
  if (t < 256) {
    const float cv = g_R[(size_t)ii.v[c] * DIM + t];
    myc = cv;
    g_centT[t * KC + c] = cv;
    red[t] = cv * cv;
  }
  __syncthreads();
  for (int o = 128; o > 0; o >>= 1) {
    if (t < o) red[t] += red[t + o];
    __syncthreads();
  }
  if (t == 0) g_csq[c] = red[0];
  grid_barrier(c, base + (++bar));

  for (int it = 0; it <= KM_ITERS; ++it) {
    const bool final_pass = (it == KM_ITERS);

    // ---- load Cs from centT (coalesced cached loads; fresh after barrier) --
    {
      float4* Cs4 = (float4*)Cs;
      const float4* T4 = (const float4*)g_centT;
      for (int i = t; i < (DIM * KC) / 4; i += 1024) Cs4[i] = T4[i];
    }
    const float cs0 = g_csq[ct + 0];
    const float cs1 = g_csq[ct + 1];
    const float cs2 = g_csq[ct + 2];
    const float cs3 = g_csq[ct + 3];

    // ---- assign two 64-point halves: thread = (point, 4-cluster group) ----
    for (int h = 0; h < 2; ++h) {
      __syncthreads();  // protect Xs reuse (and cover Cs load on h==0)
      for (int idx = t; idx < 64 * (DIM / 4); idx += 1024) {
        const int r = idx >> 6;
        const int dq = idx & 63;
        *(float4*)&Xs[r * XPITCH + dq * 4] =
            *(const float4*)(g_R + (size_t)(p0 + h * 64 + r) * DIM + dq * 4);
      }
      __syncthreads();

      // exact per-(point,cluster) fmaf chains (d ascending, same nesting)
      float a0 = 0.f, a1 = 0.f, a2 = 0.f, a3 = 0.f;
#pragma unroll 4
      for (int d = 0; d < DIM; d += 4) {
        const float4 cv0 = *(const float4*)&Cs[(d + 0) * 64 + ct];
        const float4 cv1 = *(const float4*)&Cs[(d + 1) * 64 + ct];
        const float4 cv2 = *(const float4*)&Cs[(d + 2) * 64 + ct];
        const float4 cv3 = *(const float4*)&Cs[(d + 3) * 64 + ct];
        const float4 x = *(const float4*)&Xs[plg * XPITCH + d];
        a0 = fmaf(x.x, cv0.x, fmaf(x.y, cv1.x, fmaf(x.z, cv2.x, fmaf(x.w, cv3.x, a0))));
        a1 = fmaf(x.x, cv0.y, fmaf(x.y, cv1.y, fmaf(x.z, cv2.y, fmaf(x.w, cv3.y, a1))));
        a2 = fmaf(x.x, cv0.z, fmaf(x.y, cv1.z, fmaf(x.z, cv2.z, fmaf(x.w, cv3.z, a2))));
        a3 = fmaf(x.x, cv0.w, fmaf(x.y, cv1.w, fmaf(x.z, cv2.w, fmaf(x.w, cv3.w, a3))));
      }

      const int pl = h * 64 + plg;
      const float xs = g_xsq[p0 + pl];
      float best = 3.4e38f;
      int bk = 0;
      {
        float v;
        v = (xs - 2.0f * a0) + cs0; if (v < best) { best = v; bk = ct + 0; }
        v = (xs - 2.0f * a1) + cs1; if (v < best) { best = v; bk = ct + 1; }
        v = (xs - 2.0f * a2) + cs2; if (v < best) { best = v; bk = ct + 2; }
        v = (xs - 2.0f * a3) + cs3; if (v < best) { best = v; bk = ct + 3; }
      }
      // same 16-lane butterfly (lanes = cg 0..15 for this point), same inputs
#pragma unroll
      for (int o = 1; o < 16; o <<= 1) {
        const float ov = __shfl_xor(best, o);
        const int obk = __shfl_xor(bk, o);
        if (ov < best || (ov == best && obk < bk)) { best = ov; bk = obk; }
      }
      if (cg == 0) {
        idx_s[pl] = bk;
        if (final_pass) g_idx[p0 + pl] = bk;
      }
    }
    if (final_pass) break;

    // ---- upA: thread = (cluster, 16-dim group); exact ascending-p chains --
    {
      __syncthreads();
      const int k = t >> 4;    // cluster 0..63
      const int dq = t & 15;   // dims dq*16 .. dq*16+15 (4 float4)
      float4 s[4];
#pragma unroll
      for (int q = 0; q < 4; ++q) s[q] = make_float4(0.f, 0.f, 0.f, 0.f);
      int cnt = 0;
      for (int pl = 0; pl < 64; ++pl) {
        if (idx_s[pl] == k) {
          const float4* row = (const float4*)(g_R + (size_t)(p0 + pl) * DIM) + dq * 4;
#pragma unroll
          for (int q = 0; q < 4; ++q) {
            const float4 x = row[q];
            s[q].x += x.x; s[q].y += x.y; s[q].z += x.z; s[q].w += x.w;
          }
          cnt++;
        }
      }
      for (int pl = 64; pl < 128; ++pl) {
        if (idx_s[pl] == k) {
          const float4* row = (const float4*)(&Xs[(pl - 64) * XPITCH]) + dq * 4;
#pragma unroll
          for (int q = 0; q < 4; ++q) {
            const float4 x = row[q];
            s[q].x += x.x; s[q].y += x.y; s[q].z += x.z; s[q].w += x.w;
          }
          cnt++;
        }
      }
      float4* out = (float4*)(&g_part[c][k][dq * 16]);
#pragma unroll
      for (int q = 0; q < 4; ++q) out[q] = s[q];
      if (dq == 0) g_pcnt[c][k] = cnt;
    }
    grid_barrier(c, base + (++bar));  // A: g_part/g_pcnt published + L2 inv'd

    // ---- upB for cluster c (exact chain; threads 0..255, t = dim) ----
    if (t < 256) {
      float s = 0.f;
#pragma unroll 4
      for (int ch = 0; ch < NCHUNK; ++ch) s += g_part[ch][c][t];
      int cnt = 0;
#pragma unroll 4
      for (int ch = 0; ch < NCHUNK; ++ch) cnt += g_pcnt[ch][c];
      const float nc = (cnt > 0) ? (s / (float)cnt) : myc;
      myc = nc;
      g_centT[t * KC + c] = nc;
      red[t] = nc * nc;
    }
    __syncthreads();
    for (int o = 128; o > 0; o >>= 1) {
      if (t < o) red[t] += red[t + o];
      __syncthreads();
    }
    if (t == 0) g_csq[c] = red[0];
    grid_barrier(c, base + (++bar));  // B: new centroids visible
  }
}

// mask write: out[b,h,i,j] = (cid[b,i]==cid[b,j]) ? 0 : -10000. 16 rows/block.
__global__ void __launch_bounds__(256) k_mask(float* __restrict__ out, int H) {
  const int blk = blockIdx.x;
  const int tiles = LSEQ / 16;  // 256
  const int b = blk / (H * tiles);
  const int h = (blk / tiles) % H;
  const int tile = blk % tiles;
  const int t = threadIdx.x;
  __shared__ int cid[LSEQ];  // 16 KB
  for (int j = t; j < LSEQ; j += 256) cid[j] = g_idx[b * LSEQ + j];
  __syncthreads();
  const size_t base = ((size_t)(b * H + h) * LSEQ + (size_t)tile * 16) * LSEQ;
  for (int r = 0; r < 16; ++r) {
    const int my = cid[tile * 16 + r];
    float4* orow = (float4*)(out + base + (size_t)r * LSEQ);
#pragma unroll
    for (int s = 0; s < 4; ++s) {
      const int c4 = s * 256 + t;
      const int j = c4 * 4;
      float4 v;
      v.x = (cid[j + 0] == my) ? 0.f : -10000.f;
      v.y = (cid[j + 1] == my) ? 0.f : -10000.f;
      v.z = (cid[j + 2] == my) ? 0.f : -10000.f;
      v.w = (cid[j + 3] == my) ? 0.f : -10000.f;
      orow[c4] = v;
    }
  }
}

// ---------------- launch -----------------------------------------------------
extern "C" void kernel_launch(void* const* d_in, const int* in_sizes, int n_in,
                              void* d_out, int out_size, void* d_ws, size_t ws_size,
                              hipStream_t stream) {
  const float* qk = (const float*)d_in[0];
  const float* W = (const float*)d_in[1];
  const int H = out_size / (NB * LSEQ * LSEQ);  // 8

  const InitIdx ii = compute_init_indices();  // pure host integer math

  k_R_xsq<<<NB * (LSEQ / 8), 256, 0, stream>>>(qk, W);
  k_kmeans<<<NBLK, 1024, 0, stream>>>(ii);
  k_mask<<<NB * H * (LSEQ / 16), 256, 0, stream>>>((float*)d_out, H);
}

// Round 11
// 741.354 us; speedup vs baseline: 1.6525x; 1.0188x over previous
//
#include <hip/hip_runtime.h>
#include <stdint.h>
#include <stddef.h>
#include <vector>
#include <algorithm>
#include <utility>

// Problem constants (B=2, L=4096, D=256, H=8, K=sqrt(L)=64, 10 Lloyd iters)
#define NPTS 8192
#define DIM  256
#define KC   64
#define LSEQ 4096
#define NB   2
#define KM_ITERS 10
#define NCHUNK 64     // 8192/128 points per summation chunk (bit-exact structure)
#define NBLK 64       // persistent kmeans blocks (block = chunk = cluster)
#define XPITCH 260    // padded LDS row for X tile (1040 B, 16B-aligned rows)
#define PPITCH 257    // padded LDS row for chunk-partials (combine reads 2-way free)

// JAX threefry mode: 1 = partitionable (default since jax 0.4.36), 0 = original
#define JAX_THREEFRY_PARTITIONABLE 1

// ---------------- static device scratch (fully rewritten every call) --------
__device__ float g_R[NPTS * DIM];          // 8 MB   rotated points (read-only in kmeans)
__device__ float g_xsq[NPTS];              // 32 KB  per-point squared norm
__device__ float g_centT[DIM * KC];        // 64 KB  centroids transposed [d][k]
__device__ float g_csq[KC];                // per-centroid squared norm
__device__ int   g_idx[NPTS];              // assignments (every iter; final = cid)

// Flag-tree grid barrier state (monotone across graph replays; each block
// reads its own flag at entry as base — deterministic per replay).
__device__ unsigned g_arrive[NBLK * 16];   // block c uses g_arrive[c*16]
__device__ unsigned g_release2;            // release word (monotone)

// Round-7 barrier (best measured): arrival release-store (one L2 wb), block-0
// parallel relaxed polls, single release store + acquire-inv per block.
__device__ __forceinline__ void grid_barrier(int c, unsigned target) {
  __syncthreads();
  const int t = threadIdx.x;
  if (t == 0) {
    __hip_atomic_store(&g_arrive[c * 16], target, __ATOMIC_RELEASE,
                       __HIP_MEMORY_SCOPE_AGENT);
  }
  if (c == 0) {
    if (t < NBLK) {
      while (__hip_atomic_load(&g_arrive[t * 16], __ATOMIC_RELAXED,
                               __HIP_MEMORY_SCOPE_AGENT) < target) {
        __builtin_amdgcn_s_sleep(1);
      }
    }
    __syncthreads();
    if (t == 0) {
      __hip_atomic_store(&g_release2, target, __ATOMIC_RELEASE,
                         __HIP_MEMORY_SCOPE_AGENT);
      (void)__hip_atomic_load(&g_release2, __ATOMIC_ACQUIRE,
                              __HIP_MEMORY_SCOPE_AGENT);  // single inv
    }
  } else {
    if (t == 0) {
      while (__hip_atomic_load(&g_release2, __ATOMIC_RELAXED,
                               __HIP_MEMORY_SCOPE_AGENT) < target) {
        __builtin_amdgcn_s_sleep(2);
      }
      (void)__hip_atomic_load(&g_release2, __ATOMIC_ACQUIRE,
                              __HIP_MEMORY_SCOPE_AGENT);  // single inv
    }
  }
  __syncthreads();
}

// ---------------- host threefry2x32 (exact JAX semantics) -------------------
static inline uint32_t rotl32(uint32_t x, int r) { return (x << r) | (x >> (32 - r)); }

static void threefry2x32(uint32_t k0, uint32_t k1, uint32_t x0, uint32_t x1,
                         uint32_t& o0, uint32_t& o1) {
  const uint32_t ks0 = k0, ks1 = k1, ks2 = k0 ^ k1 ^ 0x1BD11BDAu;
  const int r1[4] = {13, 15, 26, 6}, r2[4] = {17, 29, 16, 24};
  x0 += ks0; x1 += ks1;
  for (int i = 0; i < 4; ++i) { x0 += x1; x1 = rotl32(x1, r1[i]); x1 ^= x0; }
  x0 += ks1; x1 += ks2 + 1u;
  for (int i = 0; i < 4; ++i) { x0 += x1; x1 = rotl32(x1, r2[i]); x1 ^= x0; }
  x0 += ks2; x1 += ks0 + 2u;
  for (int i = 0; i < 4; ++i) { x0 += x1; x1 = rotl32(x1, r1[i]); x1 ^= x0; }
  x0 += ks0; x1 += ks1 + 3u;
  for (int i = 0; i < 4; ++i) { x0 += x1; x1 = rotl32(x1, r2[i]); x1 ^= x0; }
  x0 += ks1; x1 += ks2 + 4u;
  for (int i = 0; i < 4; ++i) { x0 += x1; x1 = rotl32(x1, r1[i]); x1 ^= x0; }
  x0 += ks2; x1 += ks0 + 5u;
  o0 = x0; o1 = x1;
}

struct InitIdx { int v[KC]; };

// jax.random.choice(key(42), 8192, (64,), replace=False)
//  = permutation(key, arange(8192))[:64]  (2-round threefry shuffle)
static InitIdx compute_init_indices() {
  uint32_t k0 = 0u, k1 = 42u;  // jax.random.key(42) -> [0, 42]
  std::vector<int> val(NPTS);
  for (int i = 0; i < NPTS; ++i) val[i] = i;
  std::vector<std::pair<uint32_t, int>> kv(NPTS);
  for (int round = 0; round < 2; ++round) {
    uint32_t nk0, nk1, sk0, sk1;
#if JAX_THREEFRY_PARTITIONABLE
    threefry2x32(k0, k1, 0u, 0u, nk0, nk1);
    threefry2x32(k0, k1, 0u, 1u, sk0, sk1);
    k0 = nk0; k1 = nk1;
    for (int i = 0; i < NPTS; ++i) {
      uint32_t o0, o1;
      threefry2x32(sk0, sk1, 0u, (uint32_t)i, o0, o1);
      kv[i] = std::make_pair(o0 ^ o1, val[i]);
    }
#else
    uint32_t a0, a1, b0, b1;
    threefry2x32(k0, k1, 0u, 2u, a0, a1);
    threefry2x32(k0, k1, 1u, 3u, b0, b1);
    nk0 = a0; nk1 = b0; sk0 = a1; sk1 = b1;
    k0 = nk0; k1 = nk1;
    for (int i = 0; i < NPTS / 2; ++i) {
      uint32_t o0, o1;
      threefry2x32(sk0, sk1, (uint32_t)i, (uint32_t)(i + NPTS / 2), o0, o1);
      kv[i] = std::make_pair(o0, 0);
      kv[i + NPTS / 2] = std::make_pair(o1, 0);
    }
    for (int i = 0; i < NPTS; ++i) kv[i].second = val[i];
#endif
    std::stable_sort(kv.begin(), kv.end(),
                     [](const std::pair<uint32_t, int>& a,
                        const std::pair<uint32_t, int>& b) { return a.first < b.first; });
    for (int i = 0; i < NPTS; ++i) val[i] = kv[i].second;
  }
  InitIdx ii;
  for (int k = 0; k < KC; ++k) ii.v[k] = val[k];
  return ii;
}

// ---------------- kernels ---------------------------------------------------

// Fused R-GEMM + xsq (unchanged).
__global__ void __launch_bounds__(256) k_R_xsq(const float* __restrict__ qk,
                                               const float* __restrict__ W) {
  __shared__ float q[8][DIM];
  const int blk = blockIdx.x;               // 0..1023
  const int b = blk / (LSEQ / 8);
  const int r0 = (blk % (LSEQ / 8)) * 8;
  const int t = threadIdx.x;
  for (int r = 0; r < 8; ++r)
    q[r][t] = qk[((size_t)b * LSEQ + r0 + r) * DIM + t];
  __syncthreads();
  float acc[8] = {0.f, 0.f, 0.f, 0.f, 0.f, 0.f, 0.f, 0.f};
  const float* Wb = W + (size_t)b * DIM * DIM;
  for (int d = 0; d < DIM; ++d) {
    const float w = Wb[d * DIM + t];
#pragma unroll
    for (int r = 0; r < 8; ++r) acc[r] = fmaf(q[r][d], w, acc[r]);
  }
  for (int r = 0; r < 8; ++r)
    g_R[((size_t)b * LSEQ + r0 + r) * DIM + t] = acc[r];
  __syncthreads();
  for (int r = 0; r < 8; ++r) q[r][t] = acc[r];
  __syncthreads();
  const int w = t >> 6, lane = t & 63;
#pragma unroll
  for (int rr = 0; rr < 2; ++rr) {
    const int r = w * 2 + rr;
    const float4 x = *(const float4*)&q[r][lane * 4];
    float s = x.x * x.x + x.y * x.y + x.z * x.z + x.w * x.w;
    for (int o = 32; o > 0; o >>= 1) s += __shfl_xor(s, o);
    if (lane == 0) g_xsq[(size_t)b * LSEQ + r0 + r] = s;
  }
}

// Persistent k-means, 64 blocks x 1024 threads. g_part is GONE: block c
// computes cluster c's centroid directly — thread (ch,dq) builds chunk ch's
// partial for cluster c with the exact ascending-p float4 chains, partials
// staged in LDS, combined in exact ascending chunk order. All fp chains are
// the same per-(point,cluster)/per-(cluster,dim) sequences as rounds 4-10
// -> bit-identical trajectory. Cross-block data per iter: g_idx(32KB) +
// centT(64KB) + csq only.
__global__ void __launch_bounds__(1024) k_kmeans(InitIdx ii) {
  __shared__ __align__(16) float CsBuf[NCHUNK * PPITCH];  // 65.8 KB: Cs[d*64+k] in assign; partials [ch][d] in cent
  __shared__ __align__(16) float Xs[64 * XPITCH];         // 66.56 KB X tile; aliased as idx_all in cent
  __shared__ float red[256];
  __shared__ int cnt_s[NCHUNK];
  __shared__ unsigned base_s;
  const int t = threadIdx.x;          // 0..1023
  const int c = blockIdx.x;           // chunk 0..63 (also the cluster this block owns)
  const int p0 = c * 128;
  const int plg = t >> 4;             // point 0..63 within current half
  const int cg = t & 15;              // 4-cluster group 0..15
  const int ct = cg * 4;

  if (t == 0)
    base_s = __hip_atomic_load(&g_arrive[c * 16], __ATOMIC_RELAXED,
                               __HIP_MEMORY_SCOPE_AGENT);
  __syncthreads();
  const unsigned base = base_s;
  unsigned bar = 0;

  // ---- init centroid k=c (exact chain, threads 0..255) ----
  float myc = 0.f;
  if (t < 256) {
    const float cv = g_R[(size_t)ii.v[c] * DIM + t];
    myc = cv;
    g_centT[t * KC + c] = cv;
    red[t] = cv * cv;
  }
  __syncthreads();
  for (int o = 128; o > 0; o >>= 1) {
    if (t < o) red[t] += red[t + o];
    __syncthreads();
  }
  if (t == 0) g_csq[c] = red[0];
  grid_barrier(c, base + (++bar));

  for (int it = 0; it <= KM_ITERS; ++it) {
    const bool final_pass = (it == KM_ITERS);

    // ---- load Cs from centT (coalesced cached loads; fresh after barrier) --
    {
      float4* Cs4 = (float4*)CsBuf;
      const float4* T4 = (const float4*)g_centT;
      for (int i = t; i < (DIM * KC) / 4; i += 1024) Cs4[i] = T4[i];
    }
    const float cs0 = g_csq[ct + 0];
    const float cs1 = g_csq[ct + 1];
    const float cs2 = g_csq[ct + 2];
    const float cs3 = g_csq[ct + 3];

    // ---- assign two 64-point halves: thread = (point, 4-cluster group) ----
    for (int h = 0; h < 2; ++h) {
      __syncthreads();  // protect Xs reuse (and cover Cs load on h==0)
      for (int idx = t; idx < 64 * (DIM / 4); idx += 1024) {
        const int r = idx >> 6;
        const int dq = idx & 63;
        *(float4*)&Xs[r * XPITCH + dq * 4] =
            *(const float4*)(g_R + (size_t)(p0 + h * 64 + r) * DIM + dq * 4);
      }
      __syncthreads();

      // exact per-(point,cluster) fmaf chains (d ascending, same nesting)
      float a0 = 0.f, a1 = 0.f, a2 = 0.f, a3 = 0.f;
#pragma unroll 4
      for (int d = 0; d < DIM; d += 4) {
        const float4 cv0 = *(const float4*)&CsBuf[(d + 0) * 64 + ct];
        const float4 cv1 = *(const float4*)&CsBuf[(d + 1) * 64 + ct];
        const float4 cv2 = *(const float4*)&CsBuf[(d + 2) * 64 + ct];
        const float4 cv3 = *(const float4*)&CsBuf[(d + 3) * 64 + ct];
        const float4 x = *(const float4*)&Xs[plg * XPITCH + d];
        a0 = fmaf(x.x, cv0.x, fmaf(x.y, cv1.x, fmaf(x.z, cv2.x, fmaf(x.w, cv3.x, a0))));
        a1 = fmaf(x.x, cv0.y, fmaf(x.y, cv1.y, fmaf(x.z, cv2.y, fmaf(x.w, cv3.y, a1))));
        a2 = fmaf(x.x, cv0.z, fmaf(x.y, cv1.z, fmaf(x.z, cv2.z, fmaf(x.w, cv3.z, a2))));
        a3 = fmaf(x.x, cv0.w, fmaf(x.y, cv1.w, fmaf(x.z, cv2.w, fmaf(x.w, cv3.w, a3))));
      }

      const int pl = h * 64 + plg;
      const float xs = g_xsq[p0 + pl];
      float best = 3.4e38f;
      int bk = 0;
      {
        float v;
        v = (xs - 2.0f * a0) + cs0; if (v < best) { best = v; bk = ct + 0; }
        v = (xs - 2.0f * a1) + cs1; if (v < best) { best = v; bk = ct + 1; }
        v = (xs - 2.0f * a2) + cs2; if (v < best) { best = v; bk = ct + 2; }
        v = (xs - 2.0f * a3) + cs3; if (v < best) { best = v; bk = ct + 3; }
      }
      // same 16-lane butterfly (lanes = cg 0..15 for this point), same inputs
#pragma unroll
      for (int o = 1; o < 16; o <<= 1) {
        const float ov = __shfl_xor(best, o);
        const int obk = __shfl_xor(bk, o);
        if (ov < best || (ov == best && obk < bk)) { best = ov; bk = obk; }
      }
      if (cg == 0) g_idx[p0 + pl] = bk;   // publish every iteration (tiny)
    }
    if (final_pass) break;
    grid_barrier(c, base + (++bar));  // A: all assignments visible

    // ---- cent phase: block c computes centroid c (exact chunked chains) ----
    {
      // load all 8192 assignments into LDS (overlay on Xs; Xs reloaded next iter)
      int* idxa = (int*)Xs;
      {
        int4* dst = (int4*)idxa;
        const int4* src = (const int4*)g_idx;
        for (int i = t; i < NPTS / 4; i += 1024) dst[i] = src[i];
      }
      __syncthreads();

      // thread (ch, dq): chunk ch's partial for cluster c, dims dq*16..+15,
      // ascending p within chunk — identical chain to the old upA.
      const int ch = t >> 4;
      const int dq = t & 15;
      float4 s[4];
#pragma unroll
      for (int q = 0; q < 4; ++q) s[q] = make_float4(0.f, 0.f, 0.f, 0.f);
      int cnt = 0;
      const int pb = ch * 128;
      for (int j = 0; j < 128; ++j) {
        if (idxa[pb + j] == c) {
          const float4* row = (const float4*)(g_R + (size_t)(pb + j) * DIM) + dq * 4;
#pragma unroll
          for (int q = 0; q < 4; ++q) {
            const float4 x = row[q];
            s[q].x += x.x; s[q].y += x.y; s[q].z += x.z; s[q].w += x.w;
          }
          ++cnt;
        }
      }
      // stage partials in LDS (CsBuf free since assign ended at barrier A)
      float* part = CsBuf;  // layout part[ch*PPITCH + d]
#pragma unroll
      for (int q = 0; q < 4; ++q)
        *(float4*)&part[ch * PPITCH + dq * 16 + q * 4] = s[q];
      if (dq == 0) cnt_s[ch] = cnt;
      __syncthreads();

      // combine in exact ascending chunk order (old upB chain), divide, csq
      if (t < 256) {
        float ssum = 0.f;
#pragma unroll 4
        for (int c2 = 0; c2 < NCHUNK; ++c2) ssum += part[c2 * PPITCH + t];
        int ctot = 0;
#pragma unroll 4
        for (int c2 = 0; c2 < NCHUNK; ++c2) ctot += cnt_s[c2];
        const float nc = (ctot > 0) ? (ssum / (float)ctot) : myc;
        myc = nc;
        g_centT[t * KC + c] = nc;
        red[t] = nc * nc;
      }
      __syncthreads();
      for (int o = 128; o > 0; o >>= 1) {
        if (t < o) red[t] += red[t + o];
        __syncthreads();
      }
      if (t == 0) g_csq[c] = red[0];
    }
    grid_barrier(c, base + (++bar));  // B: new centroids visible
  }
}

// mask write: out[b,h,i,j] = (cid[b,i]==cid[b,j]) ? 0 : -10000. 16 rows/block.
__global__ void __launch_bounds__(256) k_mask(float* __restrict__ out, int H) {
  const int blk = blockIdx.x;
  const int tiles = LSEQ / 16;  // 256
  const int b = blk / (H * tiles);
  const int h = (blk / tiles) % H;
  const int tile = blk % tiles;
  const int t = threadIdx.x;
  __shared__ int cid[LSEQ];  // 16 KB
  for (int j = t; j < LSEQ; j += 256) cid[j] = g_idx[b * LSEQ + j];
  __syncthreads();
  const size_t base = ((size_t)(b * H + h) * LSEQ + (size_t)tile * 16) * LSEQ;
  for (int r = 0; r < 16; ++r) {
    const int my = cid[tile * 16 + r];
    float4* orow = (float4*)(out + base + (size_t)r * LSEQ);
#pragma unroll
    for (int s = 0; s < 4; ++s) {
      const int c4 = s * 256 + t;
      const int j = c4 * 4;
      float4 v;
      v.x = (cid[j + 0] == my) ? 0.f : -10000.f;
      v.y = (cid[j + 1] == my) ? 0.f : -10000.f;
      v.z = (cid[j + 2] == my) ? 0.f : -10000.f;
      v.w = (cid[j + 3] == my) ? 0.f : -10000.f;
      orow[c4] = v;
    }
  }
}

// ---------------- launch -----------------------------------------------------
extern "C" void kernel_launch(void* const* d_in, const int* in_sizes, int n_in,
                              void* d_out, int out_size, void* d_ws, size_t ws_size,
                              hipStream_t stream) {
  const float* qk = (const float*)d_in[0];
  const float* W = (const float*)d_in[1];
  const int H = out_size / (NB * LSEQ * LSEQ);  // 8

  const InitIdx ii = compute_init_indices();  // pure host integer math

  k_R_xsq<<<NB * (LSEQ / 8), 256, 0, stream>>>(qk, W);
  k_kmeans<<<NBLK, 1024, 0, stream>>>(ii);
  k_mask<<<NB * H * (LSEQ / 16), 256, 0, stream>>>((float*)d_out, H);
}